// Round 16
// baseline (436.072 us; speedup 1.0000x reference)
//
#include <hip/hip_runtime.h>

#define AANG 180
#define NN 256
#define BCH 12

#ifndef M_PI
#define M_PI 3.14159265358979323846
#endif

__device__ __forceinline__ int iclamp(int v, int lo, int hi) {
    return v < lo ? lo : (v > hi ? hi : v);
}

// ---------------- Radon v12 (R15): R8-exact per-sample math, SIX-angle ILP
// (1 pass x 6 angles), wtrans prologue. LDS 159,256 B.
#define LSTR 259
#define LROWSMAX 130

__global__ __launch_bounds__(1024, 1)
void radon_kernel(const float* __restrict__ x, float* __restrict__ partial,
                  const float* __restrict__ Wq, const float* __restrict__ Wk,
                  const float* __restrict__ Wv, float* __restrict__ WqT,
                  float* __restrict__ WkT, float* __restrict__ WvT) {
    __shared__ float tile[LROWSMAX * LSTR];  // 134,680 B
    __shared__ float red[6][1024];           // + 24 KB
    int blk = blockIdx.x;        // ((n*2)+h)*30 + g
    int tid = threadIdx.x;

    // --- wtrans prologue: 720 blocks x 45 elements = 32400 (exact) ---
    if (tid < 45) {
        int idx = blk * 45 + tid;
        int p = idx / AANG;
        int j = idx - p * AANG;
        int src = j * AANG + p;
        WqT[idx] = Wq[src];
        WkT[idx] = Wk[src];
        WvT[idx] = Wv[src];
    }

    int g = blk % 30;
    int t = blk / 30;
    int h = t & 1;
    int n = t >> 1;
    int lx = tid & 255;
    int qid = tid >> 8;
    int R0 = h ? 127 : -1;
    int nrows = h ? 130 : 129;
    unsigned lrmax = h ? 128u : 127u;  // valid lr in [0, lrmax]
    const float* img = x + (size_t)n * NN * NN;

    for (int rr = qid; rr < nrows; rr += 4) {
        int gr = R0 + rr;
        bool rok = (gr >= 0) && (gr < NN);
        const float* row = img + gr * NN;
        int gc = lx - 1;
        tile[rr * LSTR + lx] = (rok && gc >= 0) ? row[gc] : 0.0f;
        if (lx < 3) {
            int gc2 = 255 + lx;
            tile[rr * LSTR + 256 + lx] = (rok && gc2 < NN) ? row[gc2] : 0.0f;
        }
    }
    __syncthreads();

    float fx = (float)lx;
    int ubase = qid * 64;

    // 6 angles a = g + k*30, k=0..5 — all in one pass (6 independent chains).
    float c[6], s[6], xcon[6], dcon[6], acc[6];
#pragma unroll
    for (int k = 0; k < 6; ++k) {
        int a = g + k * 30;
        float th = (float)((double)a * (M_PI / 180.0));
        c[k] = cosf(th);
        s[k] = sinf(th);
        float kx = -128.0f * (c[k] + s[k] - 1.0f);
        float ky = -128.0f * (c[k] - s[k] - 1.0f);
        xcon[k] = c[k] * fx + kx;    // sx = fma(s, fy, xcon)
        dcon[k] = -s[k] * fx + ky;   // sy = fma(c, fy, dcon)
        acc[k] = 0.0f;
    }
    for (int i = 0; i < 64; ++i) {
        float fy = (float)(ubase + i);
#pragma unroll
        for (int k = 0; k < 6; ++k) {
            float sy = __builtin_fmaf(c[k], fy, dcon[k]);
            float sx = __builtin_fmaf(s[k], fy, xcon[k]);
            float iyf = floorf(sy), ixf = floorf(sx);
            int lr = (int)iyf - R0, lc = (int)ixf + 1;
            if ((unsigned)lr <= lrmax && (unsigned)lc <= 256u) {
                float wy = sy - iyf, wx = sx - ixf;
                const float* tp = &tile[lr * LSTR + lc];
                float v00 = tp[0], v01 = tp[1];
                float v10 = tp[LSTR], v11 = tp[LSTR + 1];
                float wx1 = 1.0f - wx, wy1 = 1.0f - wy;
                acc[k] += wy1 * (wx1 * v00 + wx * v01) + wy * (wx1 * v10 + wx * v11);
            }
        }
    }
#pragma unroll
    for (int k = 0; k < 6; ++k) red[k][tid] = acc[k];
    __syncthreads();
    if (tid < 256) {
        size_t base = (((size_t)h * BCH + n) * AANG);
#pragma unroll
        for (int k = 0; k < 6; ++k) {
            float r = red[k][tid] + red[k][tid + 256] + red[k][tid + 512] + red[k][tid + 768];
            partial[(base + (g + k * 30)) * NN + tid] = r;
        }
    }
}

// ---------------- QKV v7 (R13): 8 rows/block. Q,V row-major; Kt scatter-stores.
__global__ void qkv_kernel(const float* __restrict__ partial,
                           const float* __restrict__ WqT, const float* __restrict__ bq,
                           const float* __restrict__ WkT, const float* __restrict__ bk,
                           const float* __restrict__ WvT, const float* __restrict__ bv,
                           float* __restrict__ Q, float* __restrict__ Kt,
                           float* __restrict__ V) {
    __shared__ float srow_t[AANG][8];
    int blk = blockIdx.x;  // n*32 + i8
    int n = blk >> 5;
    int i0 = (blk & 31) * 8;
    int tid = threadIdx.x;  // 256
    const size_t HOFF = (size_t)BCH * AANG * NN;
    if (tid < AANG) {
        size_t idx = (((size_t)n) * AANG + tid) * NN + i0;
        float4 p0 = *(const float4*)&partial[idx];
        float4 p1 = *(const float4*)&partial[idx + 4];
        float4 q0 = *(const float4*)&partial[idx + HOFF];
        float4 q1 = *(const float4*)&partial[idx + HOFF + 4];
        srow_t[tid][0] = p0.x + q0.x;
        srow_t[tid][1] = p0.y + q0.y;
        srow_t[tid][2] = p0.z + q0.z;
        srow_t[tid][3] = p0.w + q0.w;
        srow_t[tid][4] = p1.x + q1.x;
        srow_t[tid][5] = p1.y + q1.y;
        srow_t[tid][6] = p1.z + q1.z;
        srow_t[tid][7] = p1.w + q1.w;
    }
    __syncthreads();
    if (tid < AANG) {
        int j = tid;
        float aq[8], ak[8], av[8];
        float bqv = bq[j], bkv = bk[j], bvv = bv[j];
        for (int r = 0; r < 8; ++r) { aq[r] = bqv; ak[r] = bkv; av[r] = bvv; }
#pragma unroll 4
        for (int p = 0; p < AANG; ++p) {
            float wq = WqT[p * AANG + j];
            float wk = WkT[p * AANG + j];
            float wv = WvT[p * AANG + j];
            float4 sv0 = *(const float4*)&srow_t[p][0];
            float4 sv1 = *(const float4*)&srow_t[p][4];
            aq[0] += sv0.x * wq; ak[0] += sv0.x * wk; av[0] += sv0.x * wv;
            aq[1] += sv0.y * wq; ak[1] += sv0.y * wk; av[1] += sv0.y * wv;
            aq[2] += sv0.z * wq; ak[2] += sv0.z * wk; av[2] += sv0.z * wv;
            aq[3] += sv0.w * wq; ak[3] += sv0.w * wk; av[3] += sv0.w * wv;
            aq[4] += sv1.x * wq; ak[4] += sv1.x * wk; av[4] += sv1.x * wv;
            aq[5] += sv1.y * wq; ak[5] += sv1.y * wk; av[5] += sv1.y * wv;
            aq[6] += sv1.z * wq; ak[6] += sv1.z * wk; av[6] += sv1.z * wv;
            aq[7] += sv1.w * wq; ak[7] += sv1.w * wk; av[7] += sv1.w * wv;
        }
        for (int r = 0; r < 8; ++r) {
            size_t qb = ((size_t)(n * NN + i0 + r)) * AANG + j;
            Q[qb] = aq[r];  // coalesced over j
            V[qb] = av[r];  // row-major, coalesced over j (PV reads coalesced)
        }
        size_t kb = ((size_t)(n * AANG + j)) * NN + i0;
        *(float4*)&Kt[kb]     = make_float4(ak[0], ak[1], ak[2], ak[3]);
        *(float4*)&Kt[kb + 4] = make_float4(ak[4], ak[5], ak[6], ak[7]);
    }
}

// ---------------- Attention v7 (R13): 8 rows/block; coalesced Kt/V streams. ----
__global__ void attn_kernel(const float* __restrict__ Q, const float* __restrict__ Kt,
                            const float* __restrict__ V, float* __restrict__ att_t) {
    __shared__ float qrow[8][AANG];
    __shared__ float prob[8][NN];
    __shared__ float wm[8][4], wsm[8][4];
    int blk = blockIdx.x;  // n*32 + i8
    int n = blk >> 5;
    int i0 = (blk & 31) * 8;
    int tid = threadIdx.x;  // 256: key index k
    int wid = tid >> 6;
    if (tid < AANG) {
#pragma unroll
        for (int r = 0; r < 8; ++r)
            qrow[r][tid] = Q[((size_t)(n * NN + i0 + r)) * AANG + tid];
    }
    __syncthreads();
    float d[8];
#pragma unroll
    for (int r = 0; r < 8; ++r) d[r] = 0.0f;
    const float* kcol = Kt + (size_t)n * AANG * NN + tid;  // lane k: coalesced
#pragma unroll 3
    for (int jj = 0; jj < AANG / 4; ++jj) {
        float kv0 = kcol[(size_t)(jj * 4 + 0) * NN];
        float kv1 = kcol[(size_t)(jj * 4 + 1) * NN];
        float kv2 = kcol[(size_t)(jj * 4 + 2) * NN];
        float kv3 = kcol[(size_t)(jj * 4 + 3) * NN];
#pragma unroll
        for (int r = 0; r < 8; ++r) {
            float4 qv = *(const float4*)&qrow[r][jj * 4];
            d[r] += qv.x * kv0;
            d[r] += qv.y * kv1;
            d[r] += qv.z * kv2;
            d[r] += qv.w * kv3;
        }
    }
    const float rs = 0.0745355992f;  // 1/sqrt(180)
    float l[8], m[8], e[8], s[8];
#pragma unroll
    for (int r = 0; r < 8; ++r) { l[r] = d[r] * rs; m[r] = l[r]; }
    for (int off = 32; off > 0; off >>= 1) {
#pragma unroll
        for (int r = 0; r < 8; ++r) m[r] = fmaxf(m[r], __shfl_xor(m[r], off));
    }
    if ((tid & 63) == 0) {
#pragma unroll
        for (int r = 0; r < 8; ++r) wm[r][wid] = m[r];
    }
    __syncthreads();
#pragma unroll
    for (int r = 0; r < 8; ++r) {
        float mx = fmaxf(fmaxf(wm[r][0], wm[r][1]), fmaxf(wm[r][2], wm[r][3]));
        e[r] = expf(l[r] - mx);
        s[r] = e[r];
    }
    for (int off = 32; off > 0; off >>= 1) {
#pragma unroll
        for (int r = 0; r < 8; ++r) s[r] += __shfl_xor(s[r], off);
    }
    if ((tid & 63) == 0) {
#pragma unroll
        for (int r = 0; r < 8; ++r) wsm[r][wid] = s[r];
    }
    __syncthreads();
#pragma unroll
    for (int r = 0; r < 8; ++r) {
        float dn = wsm[r][0] + wsm[r][1] + wsm[r][2] + wsm[r][3];
        prob[r][tid] = e[r] / dn;
    }
    __syncthreads();
    if (tid < AANG) {
        float a[8];
#pragma unroll
        for (int r = 0; r < 8; ++r) a[r] = 0.0f;
        const float* vcol = V + (size_t)n * NN * AANG + tid;  // lane j: coalesced
#pragma unroll 4
        for (int kk = 0; kk < NN / 4; ++kk) {
            float v0 = vcol[(size_t)(kk * 4 + 0) * AANG];
            float v1 = vcol[(size_t)(kk * 4 + 1) * AANG];
            float v2 = vcol[(size_t)(kk * 4 + 2) * AANG];
            float v3 = vcol[(size_t)(kk * 4 + 3) * AANG];
#pragma unroll
            for (int r = 0; r < 8; ++r) {
                float4 p4 = *(const float4*)&prob[r][kk * 4];
                a[r] += p4.x * v0;
                a[r] += p4.y * v1;
                a[r] += p4.z * v2;
                a[r] += p4.w * v3;
            }
        }
        size_t ob = ((size_t)(n * AANG + tid)) * NN + i0;
        *(float4*)&att_t[ob]     = make_float4(a[0], a[1], a[2], a[3]);
        *(float4*)&att_t[ob + 4] = make_float4(a[4], a[5], a[6], a[7]);
    }
}

// ---------------- Ramp filter v2: zero-padded scol, no boundary selects. ----
__global__ void filter_kernel(const float* __restrict__ att_t, float* __restrict__ filt) {
    __shared__ float scol[512];  // [128..383] = data, rest 0
    __shared__ float coef[128];
    int blk = blockIdx.x;  // n*AANG + a
    int tid = threadIdx.x;
    const float* src = &att_t[(size_t)blk * NN];
    scol[tid] = (tid >= 128) ? src[tid - 128] : 0.0f;
    scol[tid + 256] = (tid < 128) ? src[tid + 128] : 0.0f;
    if (tid < 128) {
        float d = (float)(2 * tid + 1);
        coef[tid] = -2.0f / ((float)(M_PI * M_PI) * d * d);
    }
    __syncthreads();
    const float* c = &scol[tid + 128];
    float acc = 0.5f * c[0];
#pragma unroll 4
    for (int m = 0; m < 128; ++m) {
        int d = 2 * m + 1;
        acc += coef[m] * (c[-d] + c[d]);
    }
    filt[(size_t)blk * NN + tid] = acc;
}

// ---------------- Backprojection v4 (R9-verified): edge-padded cols[36][384]
// -> one ds_read2 per sample, no clamps. Pad cell = clamped edge value, so
// every accumulated value and the accumulation order are bit-identical to v3.
#define ACH 36
#define BPW 384
__global__ __launch_bounds__(1024)
void backproj_kernel(const float* __restrict__ filt, float* __restrict__ out) {
    __shared__ float cols[ACH][BPW];  // 55.3 KB
    __shared__ float cs[AANG], sn[AANG];
    int blk = blockIdx.x;  // n*64 + rg
    int n = blk >> 6;
    int rg = blk & 63;
    int tid = threadIdx.x;
    int col = tid & 255;
    int rslot = tid >> 8;
    int r = rg * 4 + rslot;
    if (tid < AANG) {
        float th = (float)((double)tid * (M_PI / 180.0));
        cs[tid] = cosf(th);
        sn[tid] = sinf(th);
    }
    float xr = (float)(r - 128);
    float yr = (float)(col - 128);
    float acc = 0.0f;
    const float* fb = filt + (size_t)n * AANG * NN;
    for (int ch = 0; ch < AANG / ACH; ++ch) {
        __syncthreads();
        for (int idx = tid; idx < ACH * BPW; idx += 1024) {
            int q = idx / BPW;
            int cc = idx - q * BPW;
            int srci = iclamp(cc - 64, 0, NN - 1);
            cols[q][cc] = fb[(size_t)(ch * ACH + q) * NN + srci];
        }
        __syncthreads();
#pragma unroll 4
        for (int q = 0; q < ACH; ++q) {
            int aa = ch * ACH + q;
            float t = yr * cs[aa] - xr * sn[aa] + 128.0f;
            float i0f = floorf(t);
            int i0 = (int)i0f;
            float frac = t - i0f;
            const float* p = &cols[q][i0 + 64];
            float v0 = p[0], v1 = p[1];
            float val = (1.0f - frac) * v0 + frac * v1;
            if (t >= 0.0f && t <= 255.0f) acc += val;
        }
    }
    bool inside = (xr * xr + yr * yr) <= 16384.0f;
    out[((size_t)(n * NN + r)) * NN + col] = inside ? acc * (float)(M_PI / 360.0) : 0.0f;
}

extern "C" void kernel_launch(void* const* d_in, const int* in_sizes, int n_in,
                              void* d_out, int out_size, void* d_ws, size_t ws_size,
                              hipStream_t stream) {
    const float* x  = (const float*)d_in[0];
    const float* Wq = (const float*)d_in[1];
    const float* bq = (const float*)d_in[2];
    const float* Wk = (const float*)d_in[3];
    const float* bk = (const float*)d_in[4];
    const float* Wv = (const float*)d_in[5];
    const float* bv = (const float*)d_in[6];
    float* out = (float*)d_out;
    float* ws = (float*)d_ws;

    const size_t SZ = (size_t)BCH * NN * AANG;
    float* P     = ws;           // partial[2][n][a][x]
    float* Q     = P + 2 * SZ;
    float* Kt    = Q + SZ;       // transposed: Kt[n][j][i] (attn reads coalesced)
    float* V     = Kt + SZ;      // row-major (attn PV reads coalesced)
    float* att_t = V + SZ;
    float* WqT   = att_t;        // alias: W-transposes dead before attn writes att_t
    float* WkT   = WqT + AANG * AANG;
    float* WvT   = WkT + AANG * AANG;
    float* filt  = P;            // alias: partials dead after qkv

    radon_kernel<<<BCH * 2 * 30, 1024, 0, stream>>>(x, P, Wq, Wk, Wv, WqT, WkT, WvT);
    qkv_kernel<<<BCH * (NN / 8), 256, 0, stream>>>(P, WqT, bq, WkT, bk, WvT, bv, Q, Kt, V);
    attn_kernel<<<BCH * (NN / 8), 256, 0, stream>>>(Q, Kt, V, att_t);
    filter_kernel<<<BCH * AANG, NN, 0, stream>>>(att_t, filt);
    backproj_kernel<<<BCH * (NN / 4), 1024, 0, stream>>>(filt, out);
}

// Round 17
// 417.698 us; speedup vs baseline: 1.0440x; 1.0440x over previous
//
#include <hip/hip_runtime.h>

#define AANG 180
#define NN 256
#define BCH 12

#ifndef M_PI
#define M_PI 3.14159265358979323846
#endif

__device__ __forceinline__ int iclamp(int v, int lo, int hi) {
    return v < lo ? lo : (v > hi ? hi : v);
}

// ---------------- Radon v12 (R15): R8-exact per-sample math, SIX-angle ILP
// (1 pass x 6 angles), wtrans prologue. LDS 159,256 B.
#define LSTR 259
#define LROWSMAX 130

__global__ __launch_bounds__(1024, 1)
void radon_kernel(const float* __restrict__ x, float* __restrict__ partial,
                  const float* __restrict__ Wq, const float* __restrict__ Wk,
                  const float* __restrict__ Wv, float* __restrict__ WqT,
                  float* __restrict__ WkT, float* __restrict__ WvT) {
    __shared__ float tile[LROWSMAX * LSTR];  // 134,680 B
    __shared__ float red[6][1024];           // + 24 KB
    int blk = blockIdx.x;        // ((n*2)+h)*30 + g
    int tid = threadIdx.x;

    // --- wtrans prologue: 720 blocks x 45 elements = 32400 (exact) ---
    if (tid < 45) {
        int idx = blk * 45 + tid;
        int p = idx / AANG;
        int j = idx - p * AANG;
        int src = j * AANG + p;
        WqT[idx] = Wq[src];
        WkT[idx] = Wk[src];
        WvT[idx] = Wv[src];
    }

    int g = blk % 30;
    int t = blk / 30;
    int h = t & 1;
    int n = t >> 1;
    int lx = tid & 255;
    int qid = tid >> 8;
    int R0 = h ? 127 : -1;
    int nrows = h ? 130 : 129;
    unsigned lrmax = h ? 128u : 127u;  // valid lr in [0, lrmax]
    const float* img = x + (size_t)n * NN * NN;

    for (int rr = qid; rr < nrows; rr += 4) {
        int gr = R0 + rr;
        bool rok = (gr >= 0) && (gr < NN);
        const float* row = img + gr * NN;
        int gc = lx - 1;
        tile[rr * LSTR + lx] = (rok && gc >= 0) ? row[gc] : 0.0f;
        if (lx < 3) {
            int gc2 = 255 + lx;
            tile[rr * LSTR + 256 + lx] = (rok && gc2 < NN) ? row[gc2] : 0.0f;
        }
    }
    __syncthreads();

    float fx = (float)lx;
    int ubase = qid * 64;

    // 6 angles a = g + k*30, k=0..5 — all in one pass (6 independent chains).
    float c[6], s[6], xcon[6], dcon[6], acc[6];
#pragma unroll
    for (int k = 0; k < 6; ++k) {
        int a = g + k * 30;
        float th = (float)((double)a * (M_PI / 180.0));
        c[k] = cosf(th);
        s[k] = sinf(th);
        float kx = -128.0f * (c[k] + s[k] - 1.0f);
        float ky = -128.0f * (c[k] - s[k] - 1.0f);
        xcon[k] = c[k] * fx + kx;    // sx = fma(s, fy, xcon)
        dcon[k] = -s[k] * fx + ky;   // sy = fma(c, fy, dcon)
        acc[k] = 0.0f;
    }
    for (int i = 0; i < 64; ++i) {
        float fy = (float)(ubase + i);
#pragma unroll
        for (int k = 0; k < 6; ++k) {
            float sy = __builtin_fmaf(c[k], fy, dcon[k]);
            float sx = __builtin_fmaf(s[k], fy, xcon[k]);
            float iyf = floorf(sy), ixf = floorf(sx);
            int lr = (int)iyf - R0, lc = (int)ixf + 1;
            if ((unsigned)lr <= lrmax && (unsigned)lc <= 256u) {
                float wy = sy - iyf, wx = sx - ixf;
                const float* tp = &tile[lr * LSTR + lc];
                float v00 = tp[0], v01 = tp[1];
                float v10 = tp[LSTR], v11 = tp[LSTR + 1];
                float wx1 = 1.0f - wx, wy1 = 1.0f - wy;
                acc[k] += wy1 * (wx1 * v00 + wx * v01) + wy * (wx1 * v10 + wx * v11);
            }
        }
    }
#pragma unroll
    for (int k = 0; k < 6; ++k) red[k][tid] = acc[k];
    __syncthreads();
    if (tid < 256) {
        size_t base = (((size_t)h * BCH + n) * AANG);
#pragma unroll
        for (int k = 0; k < 6; ++k) {
            float r = red[k][tid] + red[k][tid + 256] + red[k][tid + 512] + red[k][tid + 768];
            partial[(base + (g + k * 30)) * NN + tid] = r;
        }
    }
}

// ---------------- QKV v7 (R13): 8 rows/block. Q,V row-major; Kt scatter-stores.
__global__ void qkv_kernel(const float* __restrict__ partial,
                           const float* __restrict__ WqT, const float* __restrict__ bq,
                           const float* __restrict__ WkT, const float* __restrict__ bk,
                           const float* __restrict__ WvT, const float* __restrict__ bv,
                           float* __restrict__ Q, float* __restrict__ Kt,
                           float* __restrict__ V) {
    __shared__ float srow_t[AANG][8];
    int blk = blockIdx.x;  // n*32 + i8
    int n = blk >> 5;
    int i0 = (blk & 31) * 8;
    int tid = threadIdx.x;  // 256
    const size_t HOFF = (size_t)BCH * AANG * NN;
    if (tid < AANG) {
        size_t idx = (((size_t)n) * AANG + tid) * NN + i0;
        float4 p0 = *(const float4*)&partial[idx];
        float4 p1 = *(const float4*)&partial[idx + 4];
        float4 q0 = *(const float4*)&partial[idx + HOFF];
        float4 q1 = *(const float4*)&partial[idx + HOFF + 4];
        srow_t[tid][0] = p0.x + q0.x;
        srow_t[tid][1] = p0.y + q0.y;
        srow_t[tid][2] = p0.z + q0.z;
        srow_t[tid][3] = p0.w + q0.w;
        srow_t[tid][4] = p1.x + q1.x;
        srow_t[tid][5] = p1.y + q1.y;
        srow_t[tid][6] = p1.z + q1.z;
        srow_t[tid][7] = p1.w + q1.w;
    }
    __syncthreads();
    if (tid < AANG) {
        int j = tid;
        float aq[8], ak[8], av[8];
        float bqv = bq[j], bkv = bk[j], bvv = bv[j];
        for (int r = 0; r < 8; ++r) { aq[r] = bqv; ak[r] = bkv; av[r] = bvv; }
#pragma unroll 4
        for (int p = 0; p < AANG; ++p) {
            float wq = WqT[p * AANG + j];
            float wk = WkT[p * AANG + j];
            float wv = WvT[p * AANG + j];
            float4 sv0 = *(const float4*)&srow_t[p][0];
            float4 sv1 = *(const float4*)&srow_t[p][4];
            aq[0] += sv0.x * wq; ak[0] += sv0.x * wk; av[0] += sv0.x * wv;
            aq[1] += sv0.y * wq; ak[1] += sv0.y * wk; av[1] += sv0.y * wv;
            aq[2] += sv0.z * wq; ak[2] += sv0.z * wk; av[2] += sv0.z * wv;
            aq[3] += sv0.w * wq; ak[3] += sv0.w * wk; av[3] += sv0.w * wv;
            aq[4] += sv1.x * wq; ak[4] += sv1.x * wk; av[4] += sv1.x * wv;
            aq[5] += sv1.y * wq; ak[5] += sv1.y * wk; av[5] += sv1.y * wv;
            aq[6] += sv1.z * wq; ak[6] += sv1.z * wk; av[6] += sv1.z * wv;
            aq[7] += sv1.w * wq; ak[7] += sv1.w * wk; av[7] += sv1.w * wv;
        }
        for (int r = 0; r < 8; ++r) {
            size_t qb = ((size_t)(n * NN + i0 + r)) * AANG + j;
            Q[qb] = aq[r];  // coalesced over j
            V[qb] = av[r];  // row-major, coalesced over j (PV reads coalesced)
        }
        size_t kb = ((size_t)(n * AANG + j)) * NN + i0;
        *(float4*)&Kt[kb]     = make_float4(ak[0], ak[1], ak[2], ak[3]);
        *(float4*)&Kt[kb + 4] = make_float4(ak[4], ak[5], ak[6], ak[7]);
    }
}

// ---------------- Attention v7 (R13): 8 rows/block; coalesced Kt/V streams. ----
__global__ void attn_kernel(const float* __restrict__ Q, const float* __restrict__ Kt,
                            const float* __restrict__ V, float* __restrict__ att_t) {
    __shared__ float qrow[8][AANG];
    __shared__ float prob[8][NN];
    __shared__ float wm[8][4], wsm[8][4];
    int blk = blockIdx.x;  // n*32 + i8
    int n = blk >> 5;
    int i0 = (blk & 31) * 8;
    int tid = threadIdx.x;  // 256: key index k
    int wid = tid >> 6;
    if (tid < AANG) {
#pragma unroll
        for (int r = 0; r < 8; ++r)
            qrow[r][tid] = Q[((size_t)(n * NN + i0 + r)) * AANG + tid];
    }
    __syncthreads();
    float d[8];
#pragma unroll
    for (int r = 0; r < 8; ++r) d[r] = 0.0f;
    const float* kcol = Kt + (size_t)n * AANG * NN + tid;  // lane k: coalesced
#pragma unroll 3
    for (int jj = 0; jj < AANG / 4; ++jj) {
        float kv0 = kcol[(size_t)(jj * 4 + 0) * NN];
        float kv1 = kcol[(size_t)(jj * 4 + 1) * NN];
        float kv2 = kcol[(size_t)(jj * 4 + 2) * NN];
        float kv3 = kcol[(size_t)(jj * 4 + 3) * NN];
#pragma unroll
        for (int r = 0; r < 8; ++r) {
            float4 qv = *(const float4*)&qrow[r][jj * 4];
            d[r] += qv.x * kv0;
            d[r] += qv.y * kv1;
            d[r] += qv.z * kv2;
            d[r] += qv.w * kv3;
        }
    }
    const float rs = 0.0745355992f;  // 1/sqrt(180)
    float l[8], m[8], e[8], s[8];
#pragma unroll
    for (int r = 0; r < 8; ++r) { l[r] = d[r] * rs; m[r] = l[r]; }
    for (int off = 32; off > 0; off >>= 1) {
#pragma unroll
        for (int r = 0; r < 8; ++r) m[r] = fmaxf(m[r], __shfl_xor(m[r], off));
    }
    if ((tid & 63) == 0) {
#pragma unroll
        for (int r = 0; r < 8; ++r) wm[r][wid] = m[r];
    }
    __syncthreads();
#pragma unroll
    for (int r = 0; r < 8; ++r) {
        float mx = fmaxf(fmaxf(wm[r][0], wm[r][1]), fmaxf(wm[r][2], wm[r][3]));
        e[r] = expf(l[r] - mx);
        s[r] = e[r];
    }
    for (int off = 32; off > 0; off >>= 1) {
#pragma unroll
        for (int r = 0; r < 8; ++r) s[r] += __shfl_xor(s[r], off);
    }
    if ((tid & 63) == 0) {
#pragma unroll
        for (int r = 0; r < 8; ++r) wsm[r][wid] = s[r];
    }
    __syncthreads();
#pragma unroll
    for (int r = 0; r < 8; ++r) {
        float dn = wsm[r][0] + wsm[r][1] + wsm[r][2] + wsm[r][3];
        prob[r][tid] = e[r] / dn;
    }
    __syncthreads();
    if (tid < AANG) {
        float a[8];
#pragma unroll
        for (int r = 0; r < 8; ++r) a[r] = 0.0f;
        const float* vcol = V + (size_t)n * NN * AANG + tid;  // lane j: coalesced
#pragma unroll 4
        for (int kk = 0; kk < NN / 4; ++kk) {
            float v0 = vcol[(size_t)(kk * 4 + 0) * AANG];
            float v1 = vcol[(size_t)(kk * 4 + 1) * AANG];
            float v2 = vcol[(size_t)(kk * 4 + 2) * AANG];
            float v3 = vcol[(size_t)(kk * 4 + 3) * AANG];
#pragma unroll
            for (int r = 0; r < 8; ++r) {
                float4 p4 = *(const float4*)&prob[r][kk * 4];
                a[r] += p4.x * v0;
                a[r] += p4.y * v1;
                a[r] += p4.z * v2;
                a[r] += p4.w * v3;
            }
        }
        size_t ob = ((size_t)(n * AANG + tid)) * NN + i0;
        *(float4*)&att_t[ob]     = make_float4(a[0], a[1], a[2], a[3]);
        *(float4*)&att_t[ob + 4] = make_float4(a[4], a[5], a[6], a[7]);
    }
}

// ---------------- Ramp filter v2: zero-padded scol, no boundary selects. ----
__global__ void filter_kernel(const float* __restrict__ att_t, float* __restrict__ filt) {
    __shared__ float scol[512];  // [128..383] = data, rest 0
    __shared__ float coef[128];
    int blk = blockIdx.x;  // n*AANG + a
    int tid = threadIdx.x;
    const float* src = &att_t[(size_t)blk * NN];
    scol[tid] = (tid >= 128) ? src[tid - 128] : 0.0f;
    scol[tid + 256] = (tid < 128) ? src[tid + 128] : 0.0f;
    if (tid < 128) {
        float d = (float)(2 * tid + 1);
        coef[tid] = -2.0f / ((float)(M_PI * M_PI) * d * d);
    }
    __syncthreads();
    const float* c = &scol[tid + 128];
    float acc = 0.5f * c[0];
#pragma unroll 4
    for (int m = 0; m < 128; ++m) {
        int d = 2 * m + 1;
        acc += coef[m] * (c[-d] + c[d]);
    }
    filt[(size_t)blk * NN + tid] = acc;
}

// ---------------- Backprojection v5: R15's v3 sampling (clamps, proven best)
// + float4 staging (2304 b128 copies/chunk instead of 9216 scalar). Values
// and accumulation order bit-identical to v3. ----
#define ACH 36
__global__ __launch_bounds__(1024)
void backproj_kernel(const float* __restrict__ filt, float* __restrict__ out) {
    __shared__ float cols[ACH][NN];
    __shared__ float cs[AANG], sn[AANG];
    int blk = blockIdx.x;  // n*64 + rg
    int n = blk >> 6;
    int rg = blk & 63;
    int tid = threadIdx.x;
    int col = tid & 255;
    int rslot = tid >> 8;
    int r = rg * 4 + rslot;
    if (tid < AANG) {
        float th = (float)((double)tid * (M_PI / 180.0));
        cs[tid] = cosf(th);
        sn[tid] = sinf(th);
    }
    float xr = (float)(r - 128);
    float yr = (float)(col - 128);
    float acc = 0.0f;
    const float* fb = filt + (size_t)n * AANG * NN;
    for (int ch = 0; ch < AANG / ACH; ++ch) {
        __syncthreads();
        // float4 staging: ACH*NN/4 = 2304 vector copies, q = idx>>6, c4 = idx&63
        for (int idx = tid; idx < ACH * (NN / 4); idx += 1024) {
            int q = idx >> 6;
            int c4 = idx & 63;
            float4 v = *(const float4*)&fb[(size_t)(ch * ACH + q) * NN + c4 * 4];
            *(float4*)&cols[q][c4 * 4] = v;
        }
        __syncthreads();
#pragma unroll 4
        for (int q = 0; q < ACH; ++q) {
            int aa = ch * ACH + q;
            float t = yr * cs[aa] - xr * sn[aa] + 128.0f;
            float i0f = floorf(t);
            int i0 = (int)i0f;
            float frac = t - i0f;
            int c0 = iclamp(i0, 0, NN - 1);
            int c1 = iclamp(i0 + 1, 0, NN - 1);
            float val = (1.0f - frac) * cols[q][c0] + frac * cols[q][c1];
            if (t >= 0.0f && t <= 255.0f) acc += val;
        }
    }
    bool inside = (xr * xr + yr * yr) <= 16384.0f;
    out[((size_t)(n * NN + r)) * NN + col] = inside ? acc * (float)(M_PI / 360.0) : 0.0f;
}

extern "C" void kernel_launch(void* const* d_in, const int* in_sizes, int n_in,
                              void* d_out, int out_size, void* d_ws, size_t ws_size,
                              hipStream_t stream) {
    const float* x  = (const float*)d_in[0];
    const float* Wq = (const float*)d_in[1];
    const float* bq = (const float*)d_in[2];
    const float* Wk = (const float*)d_in[3];
    const float* bk = (const float*)d_in[4];
    const float* Wv = (const float*)d_in[5];
    const float* bv = (const float*)d_in[6];
    float* out = (float*)d_out;
    float* ws = (float*)d_ws;

    const size_t SZ = (size_t)BCH * NN * AANG;
    float* P     = ws;           // partial[2][n][a][x]
    float* Q     = P + 2 * SZ;
    float* Kt    = Q + SZ;       // transposed: Kt[n][j][i] (attn reads coalesced)
    float* V     = Kt + SZ;      // row-major (attn PV reads coalesced)
    float* att_t = V + SZ;
    float* WqT   = att_t;        // alias: W-transposes dead before attn writes att_t
    float* WkT   = WqT + AANG * AANG;
    float* WvT   = WkT + AANG * AANG;
    float* filt  = P;            // alias: partials dead after qkv

    radon_kernel<<<BCH * 2 * 30, 1024, 0, stream>>>(x, P, Wq, Wk, Wv, WqT, WkT, WvT);
    qkv_kernel<<<BCH * (NN / 8), 256, 0, stream>>>(P, WqT, bq, WkT, bk, WvT, bv, Q, Kt, V);
    attn_kernel<<<BCH * (NN / 8), 256, 0, stream>>>(Q, Kt, V, att_t);
    filter_kernel<<<BCH * AANG, NN, 0, stream>>>(att_t, filt);
    backproj_kernel<<<BCH * (NN / 4), 1024, 0, stream>>>(filt, out);
}